// Round 26
// baseline (23.897 us; speedup 1.0000x reference)
//
#include <hip/hip_runtime.h>

// Volume rendering composite (cumprod along chunk-row axis, per-column).
//
// R26: spread bytes over 8x more CUs. R25 (21.2us) was bandwidth-limited
// by BLOCK COUNT: ~11 MB on 16 CUs at ~25-50 GB/s/CU ~= 15-27us, matching
// the measurement. Now block = (chunk, 8-col group) -> 128 blocks on 128
// CUs. 1024 thr = 128 row-slots x 8 cols; lane owns 8 rows x 1 col of a
// 1024-row window, register-resident (d/z/feature batch-loaded, e kept in
// regs). ONE barrier per window; stitch = 128-entry LDS column prefix;
// Tcur per-lane (per-column), identical across waves -> __all exit, no
// flag protocol. This data: S@1024 ~ 47.6 >> 27.6 = -ln(EPS) -> exactly
// ONE window walked. Early exit exact to 8e-12 (telescoping; |f|<=1,
// z<8) vs 0.16 threshold. Adversarial data: more windows, exact.
// ONE dispatch, no workspace, no atomics, no fences, no memsets.

#define P 128
#define FARD 1.0e10f
#define EPS 1.0e-12f
#define CG 8              // columns per block
#define SLOTS 128         // row-slots per window (1024 / CG)
#define RPS 8             // rows per slot
#define WIN (SLOTS * RPS) // 1024 rows per window

__global__ __launch_bounds__(1024) void render_kernel(
    const float* __restrict__ density,
    const float* __restrict__ feature,
    const float* __restrict__ depth,
    float* __restrict__ out,
    int chunk, int n_chunks)
{
    __shared__ float sig[2][SLOTS][CG];           // 8 KB, double-buffered
    __shared__ float acc[SLOTS][CG][4];           // 16 KB
    const int tid = threadIdx.x;
    const int colg = tid & (CG - 1);              // 0..7
    const int slot = tid >> 3;                    // 0..127
    const int nbc = P / CG;                       // 16 col-groups per chunk
    const int c  = blockIdx.x / nbc;
    const int cg = blockIdx.x % nbc;
    const int col = cg * CG + colg;
    const bool far  = (col == P - 1);
    const bool edge = (colg == CG - 1);
    const long long cbase = (long long)c * chunk;

    float Tcur = 1.f;                             // per-column, wave-uniform
    float fa0 = 0.f, fa1 = 0.f, fa2 = 0.f, da = 0.f;

    const int nwin = chunk / WIN;                 // 8
    for (int it = 0; it < nwin; ++it) {
        const long long r0 = cbase + (long long)it * WIN + slot * RPS;

        // Batch-load the slot's rows: d, z, feature (latency overlapped).
        float dv[RPS], zv[RPS], ev[RPS], f0[RPS], f1[RPS], f2[RPS];
        #pragma unroll
        for (int r = 0; r < RPS; ++r) {
            const long long h = (r0 + r) * P + col;
            dv[r] = density[h];
            zv[r] = depth[h];
            const float* f = feature + 3 * h;
            f0[r] = f[0]; f1[r] = f[1]; f2[r] = f[2];
        }
        // Slot sum of s; e in registers.
        float sg = 0.f;
        #pragma unroll
        for (int r = 0; r < RPS; ++r) {
            float zn = __shfl_down(zv[r], 1);     // next col, same row
            if (edge) {                           // group boundary patch
                zn = zv[r];
                if (!far) zn = depth[(r0 + r) * P + col + 1];
            }
            float s = dv[r] * (far ? FARD : (zn - zv[r]));
            ev[r] = __expf(-s);
            sg += s;
        }
        sig[it & 1][slot][colg] = sg;
        __syncthreads();                          // the window's ONE barrier

        // Stitch: exclusive prefix over 128 slots + window total.
        float pre = 0.f, total = 0.f;
        for (int k = 0; k < SLOTS; ++k) {
            float v = sig[it & 1][k][colg];
            pre += (k < slot) ? v : 0.f;
            total += v;
        }
        float Trun = Tcur * __expf(-pre);         // T at slot start

        // Composite: pure register compute.
        #pragma unroll
        for (int r = 0; r < RPS; ++r) {
            float Tn = Trun * ev[r];              // running cumprod (ref)
            float wt = Trun - Tn;                 // T_i * (1 - temp_i)
            Trun = Tn;
            fa0 += wt * f0[r]; fa1 += wt * f1[r]; fa2 += wt * f2[r];
            da  += wt * zv[r];
        }

        Tcur *= __expf(-total);                   // window-end T (per col)
        if (__all(Tcur < EPS)) break;             // telescoping bound
    }

    // Reduce the 128 slot-accumulators per column (fixed order); write out.
    acc[slot][colg][0] = fa0; acc[slot][colg][1] = fa1;
    acc[slot][colg][2] = fa2; acc[slot][colg][3] = da;
    __syncthreads();
    if (tid < CG * 4) {                           // 32 outputs per block
        const int comp = tid >> 3, col2 = tid & (CG - 1);
        float s = 0.f;
        for (int k = 0; k < SLOTS; ++k) s += acc[k][col2][comp];
        const int gcol = cg * CG + col2;
        if (comp < 3) out[((long long)c * P + gcol) * 3 + comp] = s;
        else out[(long long)n_chunks * P * 3 + (long long)c * P + gcol] = s;
    }
}

extern "C" void kernel_launch(void* const* d_in, const int* in_sizes, int n_in,
                              void* d_out, int out_size, void* d_ws, size_t ws_size,
                              hipStream_t stream)
{
    const float* density = (const float*)d_in[0];
    const float* feature = (const float*)d_in[1];
    const float* depth   = (const float*)d_in[2];
    float* out = (float*)d_out;

    const int B = in_sizes[0] / P;        // 65536
    const int chunk = 8192;               // matches setup_inputs() chunk_size
    const int n_chunks = B / chunk;       // 8

    render_kernel<<<n_chunks * (P / CG), 1024, 0, stream>>>(
        density, feature, depth, out, chunk, n_chunks);
}

// Round 27
// 18.885 us; speedup vs baseline: 1.2654x; 1.2654x over previous
//
#include <hip/hip_runtime.h>

// Volume rendering composite (cumprod along chunk-row axis, per-column).
//
// R27: CU-spread WITH coalescing. R26 (CG=8) regressed because each wave
// load touched 8 half-used 32-B segments (2x transaction inflation),
// cancelling the CU gain. Here CG=32: 32 blocks (8 chunks x 4 col-
// quarters), 1024 thr = 32 slots x 32 contiguous cols -> each wave-load
// is two 128-B runs = 4 fully-used lines, same efficiency as R25's 16-
// block layout at 2x the CUs. WIN=128 rows (32 slots x RPS=4), walk ~640
// rows as R25. Register-resident strips; ONE barrier per window (sig
// double-buffered); per-column Tcur register identical across waves ->
// block-uniform __all exit. Early exit exact to 8e-12 via telescoping
// (|f|<=1, z<8) vs 0.16 threshold; adversarial data walks more windows.
// ONE dispatch, no workspace, no atomics, no fences, no memsets.

#define P 128
#define FARD 1.0e10f
#define EPS 1.0e-12f
#define CG 32             // columns per block
#define SLOTS 32          // row-slots per window
#define RPS 4             // rows per slot
#define WIN (SLOTS * RPS) // 128 rows per window

__global__ __launch_bounds__(1024) void render_kernel(
    const float* __restrict__ density,
    const float* __restrict__ feature,
    const float* __restrict__ depth,
    float* __restrict__ out,
    int chunk, int n_chunks)
{
    __shared__ float sig[2][SLOTS][CG];           // 8 KB, double-buffered
    __shared__ float acc[SLOTS][CG][4];           // 16 KB
    const int tid = threadIdx.x;
    const int colg = tid & (CG - 1);              // 0..31
    const int slot = tid >> 5;                    // 0..31
    const int c = blockIdx.x >> 2;                // chunk
    const int q = blockIdx.x & 3;                 // column quarter
    const int col = q * CG + colg;
    const bool far  = (col == P - 1);
    const bool edge = (colg == CG - 1);
    const long long cbase = (long long)c * chunk;

    float Tcur = 1.f;                             // per-column, wave-uniform
    float fa0 = 0.f, fa1 = 0.f, fa2 = 0.f, da = 0.f;

    const int nwin = chunk / WIN;                 // 64
    for (int it = 0; it < nwin; ++it) {
        const long long r0 = cbase + (long long)it * WIN + slot * RPS;

        // Batch-load the slot's rows: d, z, feature (latency overlapped).
        float dv[RPS], zv[RPS], ev[RPS], f0[RPS], f1[RPS], f2[RPS];
        #pragma unroll
        for (int r = 0; r < RPS; ++r) {
            const long long h = (r0 + r) * P + col;
            dv[r] = density[h];
            zv[r] = depth[h];
            float3 fv = ((const float3*)feature)[h];
            f0[r] = fv.x; f1[r] = fv.y; f2[r] = fv.z;
        }
        // Slot sum of s; e in registers.
        float sg = 0.f;
        #pragma unroll
        for (int r = 0; r < RPS; ++r) {
            float zn = __shfl_down(zv[r], 1);     // next col, same row
            if (edge) {                           // quarter-boundary patch
                zn = far ? zv[r] : depth[(r0 + r) * P + col + 1];
            }
            float s = dv[r] * (far ? FARD : (zn - zv[r]));
            ev[r] = __expf(-s);
            sg += s;
        }
        sig[it & 1][slot][colg] = sg;
        __syncthreads();                          // the window's ONE barrier

        // Stitch: exclusive prefix over 32 slots + window total.
        float pre = 0.f, total = 0.f;
        #pragma unroll
        for (int k = 0; k < SLOTS; ++k) {
            float v = sig[it & 1][k][colg];
            pre += (k < slot) ? v : 0.f;
            total += v;
        }
        float Trun = Tcur * __expf(-pre);         // T at slot start

        // Composite: pure register compute.
        #pragma unroll
        for (int r = 0; r < RPS; ++r) {
            float Tn = Trun * ev[r];              // running cumprod (ref)
            float wt = Trun - Tn;                 // T_i * (1 - temp_i)
            Trun = Tn;
            fa0 += wt * f0[r]; fa1 += wt * f1[r]; fa2 += wt * f2[r];
            da  += wt * zv[r];
        }

        Tcur *= __expf(-total);                   // window-end T (per col)
        if (__all(Tcur < EPS)) break;             // telescoping bound
    }

    // Reduce the 32 slot-accumulators per column (fixed order); write out.
    acc[slot][colg][0] = fa0; acc[slot][colg][1] = fa1;
    acc[slot][colg][2] = fa2; acc[slot][colg][3] = da;
    __syncthreads();
    if (tid < CG * 4) {                           // 128 outputs per block
        const int comp = tid >> 5, col2 = tid & (CG - 1);
        float s = 0.f;
        #pragma unroll
        for (int k = 0; k < SLOTS; ++k) s += acc[k][col2][comp];
        const int gcol = q * CG + col2;
        if (comp < 3) out[((long long)c * P + gcol) * 3 + comp] = s;
        else out[(long long)n_chunks * P * 3 + (long long)c * P + gcol] = s;
    }
}

extern "C" void kernel_launch(void* const* d_in, const int* in_sizes, int n_in,
                              void* d_out, int out_size, void* d_ws, size_t ws_size,
                              hipStream_t stream)
{
    const float* density = (const float*)d_in[0];
    const float* feature = (const float*)d_in[1];
    const float* depth   = (const float*)d_in[2];
    float* out = (float*)d_out;

    const int B = in_sizes[0] / P;        // 65536
    const int chunk = 8192;               // matches setup_inputs() chunk_size
    const int n_chunks = B / chunk;       // 8

    render_kernel<<<n_chunks * 4, 1024, 0, stream>>>(density, feature, depth,
                                                     out, chunk, n_chunks);
}